// Round 4
// baseline (456.786 us; speedup 1.0000x reference)
//
#include <hip/hip_runtime.h>
#include <stdint.h>

#define M_DIM 8192
#define K_DIM 4096
#define N_DIM 4096
#define QO 1024

// fast GEMM geometry: 256x256 tile, BK=64, 8 waves (2Mx4N), 128 KiB LDS dbuf
#define BM 256
#define BN 256
#define BK 64
#define NT (K_DIM / BK)     // 64
#define GX (N_DIM / BN)     // 16
#define GY (M_DIM / BM)     // 32
#define NWG (GX * GY)       // 512

// fallback tile
#define FBM 128
#define FBN 128
#define FBK 32

typedef __bf16 bf16x8_t __attribute__((ext_vector_type(8)));
typedef float f32x4_t __attribute__((ext_vector_type(4)));

__device__ __forceinline__ uint32_t f2bf_rne(float f) {
    union { float f; uint32_t u; } v; v.f = f;
    return (v.u + 0x7FFFu + ((v.u >> 16) & 1u)) >> 16;
}
__device__ __forceinline__ uint32_t pack2bf(float lo, float hi) {
    return f2bf_rne(lo) | (f2bf_rne(hi) << 16);
}

// ---- prep (merged): X fp32->bf16 and W_big build, one launch ----------------
#define NXB (M_DIM * K_DIM / 8 / 256)   // 16384 blocks for x
#define NWB (N_DIM * K_DIM / 8 / 256)   // 8192 blocks for w

__global__ __launch_bounds__(256) void prep_kernel(
    const float* __restrict__ x,
    const float* __restrict__ wrr, const float* __restrict__ wri,
    const float* __restrict__ wrj, const float* __restrict__ wrk,
    uint16_t* __restrict__ xb, uint16_t* __restrict__ wb)
{
    const int bid = blockIdx.x;
    if (bid < NXB) {
        const int i = bid * 256 + threadIdx.x;
        float4 v0 = ((const float4*)x)[2 * i];
        float4 v1 = ((const float4*)x)[2 * i + 1];
        uint4 o;
        o.x = pack2bf(v0.x, v0.y);
        o.y = pack2bf(v0.z, v0.w);
        o.z = pack2bf(v1.x, v1.y);
        o.w = pack2bf(v1.z, v1.w);
        ((uint4*)xb)[i] = o;
    } else {
        const int g = (bid - NXB) * 256 + threadIdx.x;
        const int n  = g >> 9;
        const int k8 = (g & 511) << 3;
        const int cp = n >> 10, o = n & 1023;
        const int c  = k8 >> 10, i = k8 & 1023;
        const int tsel = cp ^ c;
        const float* w = (tsel == 0) ? wrr : (tsel == 1) ? wri : (tsel == 2) ? wrj : wrk;
        const float s = ((0x428Eu >> ((cp << 2) | c)) & 1u) ? -1.0f : 1.0f;
        const float* p = w + (size_t)o * QO + i;
        float4 v0 = ((const float4*)p)[0];
        float4 v1 = ((const float4*)p)[1];
        uint4 ob;
        ob.x = pack2bf(s * v0.x, s * v0.y);
        ob.y = pack2bf(s * v0.z, s * v0.w);
        ob.z = pack2bf(s * v1.x, s * v1.y);
        ob.w = pack2bf(s * v1.z, s * v1.w);
        ((uint4*)wb)[g] = ob;
    }
}

// ---- 256x256 GEMM, (mh,ks)-phased with 1-phase-ahead fragment pipeline ------
// LDS (bytes): buf b at b*65536; A half h at +h*16384; B at +32768 + h*16384.
// Half = 128 rows x 64 cols bf16, row = 128 B. Swizzle byte ^= ((row&7)<<4),
// inverse applied on global src (rule 21). Wave wm reads ONLY A-half(wm);
// wave wn reads ONLY B-half(wn>>1) -> all 4 pieces of tile t+1 must retire
// before t+1's p0; vmcnt(2) at p2 retires them (leaves B0(t+2)).
// Phases by (mh,ks): p0=(0,ks0) p1=(0,ks1) p2=(1,ks1) p3=(1,ks0).
// A-groups read one phase ahead into alternating sets aS0/aS1 (period-2,
// static). B (all 8 frags) read at p0 (ks0 half serialized, ks1 pipelined).
// Counted lgkmcnt relies on in-order DS retirement; issue order pinned by
// asm memory fences. sched_barrier(0) after each wait (rule 18).

#define STAGEA(BUFB, h, kb) do {                                                \
    char* _d = (char*)sm + (BUFB) + (h) * 16384 + wid * 2048;                   \
    __builtin_amdgcn_global_load_lds(                                           \
        (const __attribute__((address_space(1))) void*)(gAs0 + (size_t)(h) * 128 * K_DIM + (kb)), \
        (__attribute__((address_space(3))) void*)_d, 16, 0, 0);                 \
    __builtin_amdgcn_global_load_lds(                                           \
        (const __attribute__((address_space(1))) void*)(gAs1 + (size_t)(h) * 128 * K_DIM + (kb)), \
        (__attribute__((address_space(3))) void*)(_d + 1024), 16, 0, 0);        \
} while (0)

#define STAGEB(BUFB, h, kb) do {                                                \
    char* _d = (char*)sm + (BUFB) + 32768 + (h) * 16384 + wid * 2048;           \
    __builtin_amdgcn_global_load_lds(                                           \
        (const __attribute__((address_space(1))) void*)(gBs0 + (size_t)(h) * 128 * K_DIM + (kb)), \
        (__attribute__((address_space(3))) void*)_d, 16, 0, 0);                 \
    __builtin_amdgcn_global_load_lds(                                           \
        (const __attribute__((address_space(1))) void*)(gBs1 + (size_t)(h) * 128 * K_DIM + (kb)), \
        (__attribute__((address_space(3))) void*)(_d + 1024), 16, 0, 0);        \
} while (0)

// A-group: 4 frags of (mh, ks) into dst set
#define LDA_G(dst, BUFB, mh, ks) do {                                           \
    const char* _b = smc + (BUFB) + aBase + (mh) * 8192;                        \
    _Pragma("unroll") for (int _m = 0; _m < 4; ++_m)                            \
        dst[_m] = *(const bf16x8_t*)(_b + _m * 2048 + ((ks) ? ko1 : ko0));      \
} while (0)

// B: 4 frags of one ks (n = 0..3 spans both nh)
#define LDB_KS(BUFB, ks) do {                                                   \
    const char* _b = smc + (BUFB) + bBase;                                      \
    _Pragma("unroll") for (int _n = 0; _n < 4; ++_n)                            \
        ball[_n][(ks)] = *(const bf16x8_t*)(_b + _n * 2048 + ((ks) ? ko1 : ko0)); \
} while (0)

// 16 MFMA: one (mh, ks) group x all 4 n-frags
#define MMK(G, mh, ks) do {                                                     \
    _Pragma("unroll") for (int _m = 0; _m < 4; ++_m)                            \
    _Pragma("unroll") for (int _n = 0; _n < 4; ++_n)                            \
        acc[(mh) * 4 + _m][_n] = __builtin_amdgcn_mfma_f32_16x16x32_bf16(       \
            G[_m], ball[_n][(ks)], acc[(mh) * 4 + _m][_n], 0, 0, 0);            \
} while (0)

#define FENCE() asm volatile("" ::: "memory")
#define VM4 asm volatile("s_waitcnt vmcnt(4)" ::: "memory")
#define VM2 asm volatile("s_waitcnt vmcnt(2)" ::: "memory")
#define VM0 asm volatile("s_waitcnt vmcnt(0)" ::: "memory")
#define LGKM(n) do { asm volatile("s_waitcnt lgkmcnt(" #n ")" ::: "memory");    \
                     __builtin_amdgcn_sched_barrier(0); } while (0)
#define BAR() __builtin_amdgcn_s_barrier()
#define PRIO1() __builtin_amdgcn_s_setprio(1)
#define PRIO0() __builtin_amdgcn_s_setprio(0)

// Steady-state tile. BR/BW: byte base of read/write buffer (compile-time).
// Stages: A(t1) at p0/p1 into BW; B(t2) at p2/p3 into BR.
// lgkm ledger per phase (FENCE-pinned order, oldest first):
//  p0: [g0'(4 old)] + [B.ks0(4) | g1(4), B.ks1(4)] -> LGKM(8) retires g0'+B.ks0
//  p1: [g1,B.ks1(<=8)] + [g2(4)] -> LGKM(4) retires g1+B.ks1
//  p2: [g2(<=4)] + [g3(4)] -> LGKM(4) retires g2
//  p3: [g3(<=4)] + [g0'(4, from BW)] -> LGKM(4) retires g3
// vmcnt: entering p0 {B(t+1)}=4; +2@p0 +2@p1 +2@p2 -> VM2 retires all t+1;
//        +2@p3 -> 4 entering next tile.
#define TILE_MAIN(BR, BW, t1, t2) do {                                          \
    /* p0: (mh0,ks0) */                                                         \
    LDB_KS(BR, 0); FENCE();                                                     \
    LDA_G(aS1, BR, 0, 1); LDB_KS(BR, 1);                                        \
    STAGEA(BW, 0, (t1) * BK);                                                   \
    FENCE(); BAR(); LGKM(8);                                                    \
    PRIO1(); MMK(aS0, 0, 0); PRIO0();                                           \
    FENCE(); BAR(); FENCE();                                                    \
    /* p1: (mh0,ks1) */                                                         \
    LDA_G(aS0, BR, 1, 1);                                                       \
    STAGEA(BW, 1, (t1) * BK);                                                   \
    FENCE(); BAR(); LGKM(4);                                                    \
    PRIO1(); MMK(aS1, 0, 1); PRIO0();                                           \
    FENCE(); BAR(); FENCE();                                                    \
    /* p2: (mh1,ks1) */                                                         \
    LDA_G(aS1, BR, 1, 0);                                                       \
    STAGEB(BR, 0, (t2) * BK);                                                   \
    FENCE(); BAR(); LGKM(4);                                                    \
    PRIO1(); MMK(aS0, 1, 1); PRIO0();                                           \
    VM2;                                                                        \
    FENCE(); BAR(); FENCE();                                                    \
    /* p3: (mh1,ks0); pre-read g0 of t+1 from BW (landed: VM2+bar) */           \
    LDA_G(aS0, BW, 0, 0);                                                       \
    STAGEB(BR, 1, (t2) * BK);                                                   \
    FENCE(); BAR(); LGKM(4);                                                    \
    PRIO1(); MMK(aS1, 1, 0); PRIO0();                                           \
    FENCE(); BAR(); FENCE();                                                    \
} while (0)

__global__ __launch_bounds__(512, 2) void qgemm8p_kernel(
    const uint16_t* __restrict__ Abf, const uint16_t* __restrict__ Bbf,
    const float* __restrict__ bias, float* __restrict__ C)
{
    __shared__ __align__(16) uint16_t sm[65536];   // 128 KiB

    const int tid  = threadIdx.x;
    const int wid  = tid >> 6;
    const int lane = tid & 63;
    const int wm = wid >> 2, wn = wid & 3;         // 2x4 waves, wave tile 128x64

    // XCD-aware bijective swizzle (NWG=512, %8==0)
    const int flat = blockIdx.x;
    const int swb  = ((flat & 7) << 6) | (flat >> 3);
    const int bm = swb >> 4, bn = swb & 15;
    const int aRow = bm * BM, bRow = bn * BN;

    // staging coords: LDS byte o = wid*2048 + i*1024 + lane*16 (linear dest);
    // global src pre-swizzled: lin = o ^ ((row(o)&7)<<4), row(o)&7 = lane>>3
    const int o0   = wid * 2048 + lane * 16;
    const int swzS = ((lane >> 3) & 7) << 4;
    const int lin0 = o0 ^ swzS;
    const int sr0 = lin0 >> 7, sc0 = (lin0 & 127) >> 1;
    const int sr1 = sr0 + 8,   sc1 = sc0;          // i=1: +1024 B = +8 rows

    // per-thread loop-invariant global staging bases
    const uint16_t* gAs0 = Abf + (size_t)(aRow + sr0) * K_DIM + sc0;
    const uint16_t* gAs1 = Abf + (size_t)(aRow + sr1) * K_DIM + sc1;
    const uint16_t* gBs0 = Bbf + (size_t)(bRow + sr0) * K_DIM + sc0;
    const uint16_t* gBs1 = Bbf + (size_t)(bRow + sr1) * K_DIM + sc1;

    // fragment read coords (byte offsets within a half, swizzled)
    const int fr  = lane & 15;
    const int q16 = ((lane >> 4) & 3) << 4;
    const int ko0 = q16 ^ ((fr & 7) << 4);
    const int ko1 = ko0 ^ 64;                      // ks=1: +64 B
    const int aBase = wm * 16384 + fr * 128;       // wave wm -> A-half(wm) only
    const int bBase = 32768 + (wn >> 1) * 16384 + (wn & 1) * 8192 + fr * 128;
    const char* const smc = (const char*)sm;

    f32x4_t acc[8][4];
#pragma unroll
    for (int a = 0; a < 8; ++a)
#pragma unroll
        for (int b = 0; b < 4; ++b)
            acc[a][b] = (f32x4_t){0.f, 0.f, 0.f, 0.f};

    bf16x8_t aS0[4], aS1[4];   // alternating A-group sets (period-2, static)
    bf16x8_t ball[4][2];       // all B frags of the tile [n][ks]

    // prologue: tile0 (B0,B1,A0,A1) -> buf0; B(1) -> buf1.
    // VM4 retires tile0's 8 loads, leaves {B0(1),B1(1)} = invariant.
    STAGEB(0,     0, 0);
    STAGEB(0,     1, 0);
    STAGEA(0,     0, 0);
    STAGEA(0,     1, 0);
    STAGEB(65536, 0, BK);
    STAGEB(65536, 1, BK);
    VM4;
    BAR();
    FENCE();
    LDA_G(aS0, 0, 0, 0);   // g0 of tile 0 (oldest lgkm entries at first p0)
    FENCE();

    // main loop: x2 unrolled, static buffer bases. even tile -> buf0
#pragma unroll 1
    for (int t = 0; t < NT - 2; t += 2) {
        TILE_MAIN(0,     65536, t + 1, t + 2);
        TILE_MAIN(65536, 0,     t + 2, t + 3);
    }
    {   // tile NT-2 (buf0): stage A(63) only; drain all at p2
        LDB_KS(0, 0); FENCE();
        LDA_G(aS1, 0, 0, 1); LDB_KS(0, 1);
        STAGEA(65536, 0, (NT - 1) * BK);
        FENCE(); BAR(); LGKM(8);
        PRIO1(); MMK(aS0, 0, 0); PRIO0();
        FENCE(); BAR(); FENCE();
        LDA_G(aS0, 0, 1, 1);
        STAGEA(65536, 1, (NT - 1) * BK);
        FENCE(); BAR(); LGKM(4);
        PRIO1(); MMK(aS1, 0, 1); PRIO0();
        FENCE(); BAR(); FENCE();
        LDA_G(aS1, 0, 1, 0);
        FENCE(); BAR(); LGKM(4);
        PRIO1(); MMK(aS0, 1, 1); PRIO0();
        VM0;
        FENCE(); BAR(); FENCE();
        LDA_G(aS0, 65536, 0, 0);
        FENCE(); BAR(); LGKM(4);
        PRIO1(); MMK(aS1, 1, 0); PRIO0();
        FENCE(); BAR(); FENCE();
    }
    {   // tile NT-1 (buf1): compute only
        LDB_KS(65536, 0); FENCE();
        LDA_G(aS1, 65536, 0, 1); LDB_KS(65536, 1);
        FENCE(); BAR(); LGKM(8);
        PRIO1(); MMK(aS0, 0, 0); PRIO0();
        FENCE(); BAR(); FENCE();
        LDA_G(aS0, 65536, 1, 1);
        FENCE(); BAR(); LGKM(4);
        PRIO1(); MMK(aS1, 0, 1); PRIO0();
        FENCE(); BAR(); FENCE();
        LDA_G(aS1, 65536, 1, 0);
        FENCE(); BAR(); LGKM(4);
        PRIO1(); MMK(aS0, 1, 1); PRIO0();
        FENCE(); BAR(); FENCE();
        LGKM(0);
        PRIO1(); MMK(aS1, 1, 0); PRIO0();
    }

    // epilogue: C/D layout col=lane&15, row=(lane>>4)*4+reg
    const int row0 = bm * BM + wm * 128 + ((lane >> 4) << 2);
    const int col0 = bn * BN + wn * 64 + (lane & 15);
#pragma unroll
    for (int ni = 0; ni < 4; ++ni) {
        const int col = col0 + ni * 16;
        const float bv = bias[col & (QO - 1)];
#pragma unroll
        for (int mi = 0; mi < 8; ++mi) {
            float* cptr = C + (size_t)(row0 + mi * 16) * N_DIM + col;
#pragma unroll
            for (int rr = 0; rr < 4; ++rr)
                cptr[(size_t)rr * N_DIM] = acc[mi][ni][rr] + bv;
        }
    }
}

// ---- fallback GEMM (no ws): fp32 inputs, on-the-fly bf16 convert ------------
__global__ __launch_bounds__(256) void qgemm_fb_kernel(
    const float* __restrict__ x,
    const float* __restrict__ wrr, const float* __restrict__ wri,
    const float* __restrict__ wrj, const float* __restrict__ wrk,
    const float* __restrict__ bias, float* __restrict__ C)
{
    __shared__ uint16_t lA[FBM * FBK];
    __shared__ uint16_t lB[FBN * FBK];
    const int t    = threadIdx.x;
    const int wave = t >> 6;
    const int lane = t & 63;
    const int bn = blockIdx.x, bm = blockIdx.y;
    const int wm = wave >> 1, wn = wave & 1;

    f32x4_t acc[4][4];
#pragma unroll
    for (int a = 0; a < 4; ++a)
#pragma unroll
        for (int b = 0; b < 4; ++b)
            acc[a][b] = (f32x4_t){0.f, 0.f, 0.f, 0.f};

    const int fr  = lane & 15;
    const int fkb = (lane >> 4) << 3;
    const uint16_t* pA[4];
    const uint16_t* pB[4];
#pragma unroll
    for (int i = 0; i < 4; ++i) {
        pA[i] = lA + (wm * 64 + i * 16 + fr) * FBK + fkb;
        pB[i] = lB + (wn * 64 + i * 16 + fr) * FBK + fkb;
    }

    const int mr = t >> 1;
    const int mc = (t & 1) << 4;
    int ng = bn * FBN + mr;
    int bcp = ng >> 10;
    int bo  = ng & 1023;

#pragma unroll 1
    for (int kb = 0; kb < K_DIM; kb += FBK) {
        const float* pa = x + (size_t)(bm * FBM + mr) * K_DIM + kb + mc;
        float4 a0 = ((const float4*)pa)[0], a1 = ((const float4*)pa)[1],
               a2 = ((const float4*)pa)[2], a3 = ((const float4*)pa)[3];
        uint4 wv0 = make_uint4(pack2bf(a0.x, a0.y), pack2bf(a0.z, a0.w),
                               pack2bf(a1.x, a1.y), pack2bf(a1.z, a1.w));
        uint4 wv1 = make_uint4(pack2bf(a2.x, a2.y), pack2bf(a2.z, a2.w),
                               pack2bf(a3.x, a3.y), pack2bf(a3.z, a3.w));
        *(uint4*)(lA + mr * FBK + mc)     = wv0;
        *(uint4*)(lA + mr * FBK + mc + 8) = wv1;

        int k0 = kb + mc;
        int c  = k0 >> 10, ii = k0 & 1023;
        int tsel = bcp ^ c;
        const float* w = (tsel == 0) ? wrr : (tsel == 1) ? wri : (tsel == 2) ? wrj : wrk;
        float s = ((0x428Eu >> ((bcp << 2) | c)) & 1u) ? -1.0f : 1.0f;
        const float* pb = w + (size_t)bo * QO + ii;
        float4 b0 = ((const float4*)pb)[0], b1 = ((const float4*)pb)[1],
               b2 = ((const float4*)pb)[2], b3 = ((const float4*)pb)[3];
        uint4 u0 = make_uint4(pack2bf(s * b0.x, s * b0.y), pack2bf(s * b0.z, s * b0.w),
                              pack2bf(s * b1.x, s * b1.y), pack2bf(s * b1.z, s * b1.w));
        uint4 u1 = make_uint4(pack2bf(s * b2.x, s * b2.y), pack2bf(s * b2.z, s * b2.w),
                              pack2bf(s * b3.x, s * b3.y), pack2bf(s * b3.z, s * b3.w));
        *(uint4*)(lB + mr * FBK + mc)     = u0;
        *(uint4*)(lB + mr * FBK + mc + 8) = u1;
        __syncthreads();

        bf16x8_t afr[4], bfrg[4];
#pragma unroll
        for (int i = 0; i < 4; ++i) {
            afr[i]  = *(const bf16x8_t*)pA[i];
            bfrg[i] = *(const bf16x8_t*)pB[i];
        }
#pragma unroll
        for (int mi = 0; mi < 4; ++mi)
#pragma unroll
            for (int ni = 0; ni < 4; ++ni)
                acc[mi][ni] = __builtin_amdgcn_mfma_f32_16x16x32_bf16(
                    afr[mi], bfrg[ni], acc[mi][ni], 0, 0, 0);
        __syncthreads();
    }

    const int row0 = bm * FBM + wm * 64 + ((lane >> 4) << 2);
    const int col0 = bn * FBN + wn * 64 + (lane & 15);
#pragma unroll
    for (int ni = 0; ni < 4; ++ni) {
        const int col = col0 + ni * 16;
        const float bv = bias[col & (QO - 1)];
#pragma unroll
        for (int mi = 0; mi < 4; ++mi) {
            const int r = row0 + mi * 16;
            float* cptr = C + (size_t)r * N_DIM + col;
#pragma unroll
            for (int rr = 0; rr < 4; ++rr)
                cptr[(size_t)rr * N_DIM] = acc[mi][ni][rr] + bv;
        }
    }
}

extern "C" void kernel_launch(void* const* d_in, const int* in_sizes, int n_in,
                              void* d_out, int out_size, void* d_ws, size_t ws_size,
                              hipStream_t stream) {
    const float* x   = (const float*)d_in[0];
    const float* wrr = (const float*)d_in[1];
    const float* wri = (const float*)d_in[2];
    const float* wrj = (const float*)d_in[3];
    const float* wrk = (const float*)d_in[4];
    const float* brr = (const float*)d_in[5];
    float* out = (float*)d_out;

    const size_t xb_bytes = (size_t)M_DIM * K_DIM * 2;   // 64 MiB
    const size_t wb_bytes = (size_t)N_DIM * K_DIM * 2;   // 32 MiB

    if (ws_size >= xb_bytes + wb_bytes) {
        uint16_t* xb = (uint16_t*)d_ws;
        uint16_t* wb = (uint16_t*)((char*)d_ws + xb_bytes);
        prep_kernel<<<NXB + NWB, 256, 0, stream>>>(x, wrr, wri, wrj, wrk, xb, wb);
        qgemm8p_kernel<<<dim3(NWG), dim3(512), 0, stream>>>(xb, wb, brr, out);
    } else {
        dim3 grid(N_DIM / FBN, M_DIM / FBM);
        qgemm_fb_kernel<<<grid, 256, 0, stream>>>(x, wrr, wri, wrj, wrk, brr, out);
    }
}